// Round 1
// 500.570 us; speedup vs baseline: 1.2919x; 1.2919x over previous
//
#include <hip/hip_runtime.h>
#include <math.h>

#define N_TOK 32768
#define M_EMB 1024
#define D_DIM 128
#define BN 32
#define NBLK (N_TOK / BN)

// workspace layout (bytes)
#define WS_EH  0                        // bf16 e_hi[1024][128]   (256 KB)
#define WS_EL  262144                   // bf16 e_lo[1024][128]   (256 KB)
#define WS_TH  524288                   // bf16 et_hi[128][1024]  (256 KB)
#define WS_TL  786432                   // bf16 et_lo[128][1024]  (256 KB)
#define WS_E2  1048576                  // float e2[1024]
#define WS_CNT (WS_E2 + 4096)           // int counts[1024]
#define WS_SS  (WS_CNT + 4096)          // float sum((x-q)^2)
#define WS_ENT (WS_SS + 4)              // float sum(p*logp)

#define S_STRIDE 1032                   // floats per LDS score row (4128 B, 16B-aligned)
#define LDS_BYTES (BN * S_STRIDE * 4 + 256)

typedef float  f32x4  __attribute__((ext_vector_type(4)));
typedef short  s16x8  __attribute__((ext_vector_type(8)));
typedef __bf16 bf16x8 __attribute__((ext_vector_type(8)));

__device__ __forceinline__ ushort f2bf(float f) {
    unsigned x = __float_as_uint(f);
    unsigned r = (x + 0x7fffu + ((x >> 16) & 1u)) >> 16;
    return (ushort)r;
}
__device__ __forceinline__ float bf2f(ushort h) {
    return __uint_as_float(((unsigned)h) << 16);
}
__device__ __forceinline__ f32x4 mfma16(s16x8 a, s16x8 b, f32x4 c) {
    return __builtin_amdgcn_mfma_f32_16x16x32_bf16(
        __builtin_bit_cast(bf16x8, a), __builtin_bit_cast(bf16x8, b), c, 0, 0, 0);
}

__global__ void k_zero(char* ws) {
    int* cnt = (int*)(ws + WS_CNT);
    for (int i = threadIdx.x; i < M_EMB; i += 256) cnt[i] = 0;
    if (threadIdx.x == 0) {
        *(float*)(ws + WS_SS) = 0.f;
        *(float*)(ws + WS_ENT) = 0.f;
    }
}

// Convert embedding to bf16 hi/lo in row-major and transposed layouts; compute e2.
__global__ void k_prep(const float* __restrict__ emb, char* ws) {
    __shared__ ushort th_s[16][128];
    __shared__ ushort tl_s[16][128];
    ushort* eh = (ushort*)(ws + WS_EH);
    ushort* el = (ushort*)(ws + WS_EL);
    ushort* th = (ushort*)(ws + WS_TH);
    ushort* tl = (ushort*)(ws + WS_TL);
    float* e2 = (float*)(ws + WS_E2);
    const int m0 = blockIdx.x * 16;
    const int t = threadIdx.x;
    #pragma unroll
    for (int ii = 0; ii < 8; ii++) {
        int idx = t + ii * 256;          // 0..2047
        int mi = idx >> 7, k = idx & 127;
        float v = emb[(size_t)(m0 + mi) * D_DIM + k];
        ushort hi = f2bf(v);
        ushort lo = f2bf(v - bf2f(hi));
        eh[(size_t)(m0 + mi) * D_DIM + k] = hi;
        el[(size_t)(m0 + mi) * D_DIM + k] = lo;
        th_s[mi][k] = hi;
        tl_s[mi][k] = lo;
    }
    __syncthreads();
    {
        int k = t >> 1, half = t & 1;
        s16x8 vh, vl;
        #pragma unroll
        for (int j = 0; j < 8; j++) {
            vh[j] = (short)th_s[half * 8 + j][k];
            vl[j] = (short)tl_s[half * 8 + j][k];
        }
        *(s16x8*)(th + (size_t)k * M_EMB + m0 + half * 8) = vh;
        *(s16x8*)(tl + (size_t)k * M_EMB + m0 + half * 8) = vl;
    }
    if (t < 16) {
        float s = 0.f;
        const float* er = emb + (size_t)(m0 + t) * D_DIM;
        #pragma unroll 4
        for (int k = 0; k < 128; k++) s += er[k] * er[k];
        e2[m0 + t] = s;
    }
}

__global__ __launch_bounds__(512, 2) void k_main(
    const float* __restrict__ x, const float* __restrict__ emb,
    const float* __restrict__ lvq, const float* __restrict__ u,
    float* __restrict__ out, char* __restrict__ ws)
{
    extern __shared__ char smem[];
    float* Sm   = (float*)smem;                          // [BN][S_STRIDE] scores -> g -> p~(bf16)
    float* mg_s = (float*)(smem + BN * S_STRIDE * 4);    // [BN] gumbel row max
    float* sg_s = mg_s + BN;                             // [BN] sum exp(g-mg)

    const int t = threadIdx.x;
    const int w = t >> 6;            // wave 0..7
    const int lane = t & 63;
    const int l15 = lane & 15;
    const int h = lane >> 4;         // 0..3
    const int n0 = blockIdx.x * BN;

    const float* e2g = (const float*)(ws + WS_E2);
    int* cnt = (int*)(ws + WS_CNT);
    float* ws_ss = (float*)(ws + WS_SS);
    float* ws_ent = (float*)(ws + WS_ENT);

    const float prec = expf(-lvq[0]);
    const float hp = 0.5f * prec;

    if (t < BN) sg_s[t] = 0.f;

    // ---- A fragments: x rows (l15, 16+l15), k = ks*32 + h*8 + j ----
    s16x8 a_hi[2][4], a_lo[2][4];
    #pragma unroll
    for (int rt = 0; rt < 2; rt++) {
        const float* xr = x + (size_t)(n0 + rt * 16 + l15) * D_DIM;
        #pragma unroll
        for (int ks = 0; ks < 4; ks++) {
            const int k0 = ks * 32 + h * 8;
            float4 v0 = *(const float4*)(xr + k0);
            float4 v1 = *(const float4*)(xr + k0 + 4);
            float vv[8] = {v0.x, v0.y, v0.z, v0.w, v1.x, v1.y, v1.z, v1.w};
            s16x8 hi8, lo8;
            #pragma unroll
            for (int j = 0; j < 8; j++) {
                ushort hi = f2bf(vv[j]);
                hi8[j] = (short)hi;
                lo8[j] = (short)f2bf(vv[j] - bf2f(hi));
            }
            a_hi[rt][ks] = hi8;
            a_lo[rt][ks] = lo8;
        }
    }

    // ---- phase 1: logits GEMM via MFMA, 3-way bf16 split ----
    // s[n][m] = prec * (x.e_m) - hp * e2[m]   (row-constant -hp*x2 dropped: softmax/argmax invariant)
    const s16x8* EH = (const s16x8*)(ws + WS_EH);
    const s16x8* EL = (const s16x8*)(ws + WS_EL);
    const f32x4 zz = {0.f, 0.f, 0.f, 0.f};
    for (int i = 0; i < 8; i++) {
        const int mt = w * 8 + i;
        const int m = mt * 16 + l15;         // this lane's column
        s16x8 bh[4], bl[4];
        #pragma unroll
        for (int ks = 0; ks < 4; ks++) {
            const int bidx = m * 16 + ks * 4 + h;
            bh[ks] = EH[bidx];
            bl[ks] = EL[bidx];
        }
        f32x4 aa0 = zz, ab0 = zz, ac0 = zz, aa1 = zz, ab1 = zz, ac1 = zz;
        #pragma unroll
        for (int ks = 0; ks < 4; ks++) {
            aa0 = mfma16(a_hi[0][ks], bh[ks], aa0);
            aa1 = mfma16(a_hi[1][ks], bh[ks], aa1);
            ab0 = mfma16(a_lo[0][ks], bh[ks], ab0);
            ab1 = mfma16(a_lo[1][ks], bh[ks], ab1);
            ac0 = mfma16(a_hi[0][ks], bl[ks], ac0);
            ac1 = mfma16(a_hi[1][ks], bl[ks], ac1);
        }
        const float hpe2 = hp * e2g[m];
        #pragma unroll
        for (int j = 0; j < 4; j++) {
            float xe0 = aa0[j] + ab0[j] + ac0[j];
            float xe1 = aa1[j] + ab1[j] + ac1[j];
            Sm[(h * 4 + j) * S_STRIDE + m]        = prec * xe0 - hpe2;
            Sm[(16 + h * 4 + j) * S_STRIDE + m]   = prec * xe1 - hpe2;
        }
    }
    __syncthreads();

    // ---- phase 2a: per-row top-2 + exact fp32 recheck + entropy + gumbel ----
    const float EPS = 1.1920929e-07f, OME = 0.99999988f;
    float ent_loc = 0.f;
    #pragma unroll
    for (int rr = 0; rr < 4; rr++) {
        const int r = w * 4 + rr;
        const int n = n0 + r;
        float* row = Sm + r * S_STRIDE;
        float bv1 = -INFINITY, bv2 = -INFINITY;
        int bi1 = M_EMB, bi2 = M_EMB;
        #pragma unroll
        for (int i2 = 0; i2 < 16; i2++) {
            const int m = lane + 64 * i2;
            const float v = row[m];
            if (v > bv1 || (v == bv1 && m < bi1)) { bv2 = bv1; bi2 = bi1; bv1 = v; bi1 = m; }
            else if (v > bv2 || (v == bv2 && m < bi2)) { bv2 = v; bi2 = m; }
        }
        #pragma unroll
        for (int off = 32; off >= 1; off >>= 1) {
            const float ov1 = __shfl_xor(bv1, off); const int oi1 = __shfl_xor(bi1, off);
            const float ov2 = __shfl_xor(bv2, off); const int oi2 = __shfl_xor(bi2, off);
            if (ov1 > bv1 || (ov1 == bv1 && oi1 < bi1)) { bv2 = bv1; bi2 = bi1; bv1 = ov1; bi1 = oi1; }
            else if (ov1 > bv2 || (ov1 == bv2 && oi1 < bi2)) { bv2 = ov1; bi2 = oi1; }
            if (ov2 > bv2 || (ov2 == bv2 && oi2 < bi2)) { bv2 = ov2; bi2 = oi2; }
        }
        // exact fp32 recheck of both candidates (argmin robustness)
        {
            const size_t xb = (size_t)n * D_DIM;
            const float xa = x[xb + lane], xc = x[xb + lane + 64];
            float s1 = xa * emb[(size_t)bi1 * D_DIM + lane] + xc * emb[(size_t)bi1 * D_DIM + lane + 64];
            float s2 = xa * emb[(size_t)bi2 * D_DIM + lane] + xc * emb[(size_t)bi2 * D_DIM + lane + 64];
            #pragma unroll
            for (int off = 32; off >= 1; off >>= 1) {
                s1 += __shfl_xor(s1, off);
                s2 += __shfl_xor(s2, off);
            }
            const float g1 = prec * s1 - hp * e2g[bi1];
            const float g2 = prec * s2 - hp * e2g[bi2];
            if (g2 > g1 || (g2 == g1 && bi2 < bi1)) bi1 = bi2;
        }
        // fused entropy + gumbel (overwrite s with g in place)
        const float mx = bv1;
        float S = 0.f, T = 0.f, mg = -INFINITY;
        const float* urow = u + (size_t)n * M_EMB;
        #pragma unroll
        for (int i2 = 0; i2 < 16; i2++) {
            const int m = lane + 64 * i2;
            const float v = row[m] - mx;
            const float e = expf(v);
            S += e; T += e * v;
            float uv = urow[m];
            uv = fminf(fmaxf(uv, EPS), OME);
            const float g = row[m] - logf(-logf(uv));
            row[m] = g;
            mg = fmaxf(mg, g);
        }
        #pragma unroll
        for (int off = 32; off >= 1; off >>= 1) {
            S += __shfl_xor(S, off);
            T += __shfl_xor(T, off);
            mg = fmaxf(mg, __shfl_xor(mg, off));
        }
        if (lane == 0) {
            ent_loc += T / S - logf(S);
            out[(size_t)N_TOK * D_DIM + n] = (float)bi1;
            atomicAdd(&cnt[bi1], 1);
            mg_s[r] = mg;
        }
    }
    if (lane == 0) atomicAdd(ws_ent, ent_loc);
    __syncthreads();

    // ---- phase 2b: p~ = exp(g - mg) packed bf16 in place (wave-local window); Sg ----
    // wave w owns m in [128w, 128w+128); p~[m] stored at row byte 512*(m>>7) + 2*(m&127)
    {
        const int m0 = 128 * w + 2 * lane;
        for (int r = 0; r < BN; r++) {
            float* row = Sm + r * S_STRIDE;
            const float mgr = mg_s[r];
            const float2 g2 = *(const float2*)(row + m0);
            const float p0 = expf(g2.x - mgr);
            const float p1 = expf(g2.y - mgr);
            const unsigned pk = (unsigned)f2bf(p0) | ((unsigned)f2bf(p1) << 16);
            *(float*)((char*)row + 512 * w + 4 * lane) = __uint_as_float(pk);
            float sp = p0 + p1;
            #pragma unroll
            for (int off = 32; off >= 1; off >>= 1) sp += __shfl_xor(sp, off);
            if (lane == 0) atomicAdd(&sg_s[r], sp);
        }
    }
    __syncthreads();

    // ---- phase 3: quantized = (p~ @ E) / Sg via MFMA, E split hi+lo ----
    const s16x8* TH = (const s16x8*)(ws + WS_TH);
    const s16x8* TL = (const s16x8*)(ws + WS_TL);
    const int d = 16 * w + l15;
    f32x4 q0a = zz, q0b = zz, q1a = zz, q1b = zz;
    #pragma unroll 2
    for (int ms = 0; ms < 32; ms++) {
        const int pboff = 512 * (ms >> 2) + 64 * (ms & 3) + 16 * h;
        const s16x8 pa0 = *(const s16x8*)((const char*)(Sm + l15 * S_STRIDE) + pboff);
        const s16x8 pa1 = *(const s16x8*)((const char*)(Sm + (16 + l15) * S_STRIDE) + pboff);
        const int bidx = d * 128 + ms * 4 + h;
        const s16x8 bh = TH[bidx];
        const s16x8 bl = TL[bidx];
        q0a = mfma16(pa0, bh, q0a);
        q0b = mfma16(pa0, bl, q0b);
        q1a = mfma16(pa1, bh, q1a);
        q1b = mfma16(pa1, bl, q1b);
    }
    float ssl = 0.f;
    #pragma unroll
    for (int j = 0; j < 4; j++) {
        {
            const int r = 4 * h + j;
            const int n = n0 + r;
            const float q = (q0a[j] + q0b[j]) / sg_s[r];
            out[(size_t)n * D_DIM + d] = q;
            const float df = x[(size_t)n * D_DIM + d] - q;
            ssl += df * df;
        }
        {
            const int r = 16 + 4 * h + j;
            const int n = n0 + r;
            const float q = (q1a[j] + q1b[j]) / sg_s[r];
            out[(size_t)n * D_DIM + d] = q;
            const float df = x[(size_t)n * D_DIM + d] - q;
            ssl += df * df;
        }
    }
    #pragma unroll
    for (int off = 32; off >= 1; off >>= 1) ssl += __shfl_down(ssl, off);
    if (lane == 0) atomicAdd(ws_ss, ssl);
}

__global__ void k_final(const float* __restrict__ lvq, float* __restrict__ out, char* ws) {
    const int* cnt = (const int*)(ws + WS_CNT);
    float s = 0.f;
    for (int i = threadIdx.x; i < M_EMB; i += 256) {
        float avg = (float)cnt[i] * (1.f / N_TOK);
        s += avg * logf(avg + 1e-10f);
    }
    #pragma unroll
    for (int off = 32; off >= 1; off >>= 1) s += __shfl_down(s, off);
    __shared__ float p[4];
    if ((threadIdx.x & 63) == 0) p[threadIdx.x >> 6] = s;
    __syncthreads();
    if (threadIdx.x == 0) {
        float tot = p[0] + p[1] + p[2] + p[3];
        float perp = expf(-tot);
        float prec = expf(-lvq[0]);
        float loss = 0.5f * prec * (*(float*)(ws + WS_SS)) + (*(float*)(ws + WS_ENT));
        out[(size_t)N_TOK * D_DIM + N_TOK] = loss;
        out[(size_t)N_TOK * D_DIM + N_TOK + 1] = perp;
    }
}

extern "C" void kernel_launch(void* const* d_in, const int* in_sizes, int n_in,
                              void* d_out, int out_size, void* d_ws, size_t ws_size,
                              hipStream_t stream) {
    const float* x   = (const float*)d_in[0];
    const float* emb = (const float*)d_in[1];
    const float* lvq = (const float*)d_in[2];
    const float* u   = (const float*)d_in[3];
    float* out = (float*)d_out;
    char* ws = (char*)d_ws;
    static bool attr_done = false;
    if (!attr_done) {
        hipFuncSetAttribute((const void*)k_main,
                            hipFuncAttributeMaxDynamicSharedMemorySize, LDS_BYTES);
        attr_done = true;
    }
    k_zero<<<dim3(1), dim3(256), 0, stream>>>(ws);
    k_prep<<<dim3(M_EMB / 16), dim3(256), 0, stream>>>(emb, ws);
    k_main<<<dim3(NBLK), dim3(512), LDS_BYTES, stream>>>(x, emb, lvq, u, out, ws);
    k_final<<<dim3(1), dim3(256), 0, stream>>>(lvq, out, ws);
}